// Round 2
// baseline (706.862 us; speedup 1.0000x reference)
//
#include <hip/hip_runtime.h>

#define NBATCH 2048

typedef __attribute__((ext_vector_type(8))) short short8;
typedef __attribute__((ext_vector_type(4))) short short4v;
typedef __attribute__((ext_vector_type(4))) float f32x4;
typedef __attribute__((ext_vector_type(4))) unsigned short us4;

__device__ __forceinline__ unsigned short f2bf(float f) {
    unsigned int u = __float_as_uint(f);
    u += 0x7FFFu + ((u >> 16) & 1u);
    return (unsigned short)(u >> 16);
}

__device__ __forceinline__ short4v pack4(f32x4 v) {
    short4v r;
    r[0] = (short)f2bf(v[0]); r[1] = (short)f2bf(v[1]);
    r[2] = (short)f2bf(v[2]); r[3] = (short)f2bf(v[3]);
    return r;
}
__device__ __forceinline__ short8 pack8(f32x4 lo, f32x4 hi) {
    short8 r;
    r[0] = (short)f2bf(lo[0]); r[1] = (short)f2bf(lo[1]);
    r[2] = (short)f2bf(lo[2]); r[3] = (short)f2bf(lo[3]);
    r[4] = (short)f2bf(hi[0]); r[5] = (short)f2bf(hi[1]);
    r[6] = (short)f2bf(hi[2]); r[7] = (short)f2bf(hi[3]);
    return r;
}

__device__ __forceinline__ f32x4 mfma16(short4v a, short4v b, f32x4 c) {
#if __has_builtin(__builtin_amdgcn_mfma_f32_16x16x16bf16_1k)
    return __builtin_amdgcn_mfma_f32_16x16x16bf16_1k(a, b, c, 0, 0, 0);
#elif __has_builtin(__builtin_amdgcn_mfma_f32_16x16x16_bf16)
    return __builtin_amdgcn_mfma_f32_16x16x16_bf16(a, b, c, 0, 0, 0);
#else
    asm volatile("v_mfma_f32_16x16x16_bf16 %0, %1, %2, %0" : "+v"(c) : "v"(a), "v"(b));
    return c;
#endif
}
#define MFMA32(a, b, c) __builtin_amdgcn_mfma_f32_16x16x32_bf16(a, b, c, 0, 0, 0)

// XOR swizzle: 16B slot = f(row) so both transpose-writes and row-frag reads spread banks
#define SW(t) ((((t) ^ ((t) >> 3)) & 7) << 4)

// ws layout (bytes)
#define PMW_OFF   0u        // [4*64][64] bf16
#define THW_OFF   32768u    // [256][512] bf16
#define PHW_OFF   294912u   // [256][512] bf16
#define GW_OFF    557056u   // [256][512] bf16
#define OUTW_OFF  819200u   // [512][256] bf16 (BN-scaled)
#define OUTB_OFF  1081344u  // [512] f32 (folded BN bias)
#define WS_BYTES  1083392u

__global__ void prep_kernel(const float* __restrict__ pm_w, const float* __restrict__ g_w,
                            const float* __restrict__ th_w, const float* __restrict__ ph_w,
                            const float* __restrict__ out_w, const float* __restrict__ gamma,
                            const float* __restrict__ beta, const float* __restrict__ mean,
                            const float* __restrict__ var, char* __restrict__ ws) {
    int i = blockIdx.x * 256 + threadIdx.x;
    unsigned short* pmw = (unsigned short*)(ws + PMW_OFF);
    unsigned short* thw = (unsigned short*)(ws + THW_OFF);
    unsigned short* phw = (unsigned short*)(ws + PHW_OFF);
    unsigned short* gww = (unsigned short*)(ws + GW_OFF);
    unsigned short* oww = (unsigned short*)(ws + OUTW_OFF);
    float* ob = (float*)(ws + OUTB_OFF);
    if (i < 16384) pmw[i] = f2bf(pm_w[i]);
    if (i < 131072) {
        thw[i] = f2bf(th_w[i]);
        phw[i] = f2bf(ph_w[i]);
        gww[i] = f2bf(g_w[i]);
        int o = i >> 8;
        float inv = gamma[o] * rsqrtf(var[o] + 1e-5f);
        oww[i] = f2bf(out_w[i] * inv);
    }
    if (i < 512) {
        float inv = gamma[i] * rsqrtf(var[i] + 1e-5f);
        ob[i] = beta[i] - mean[i] * inv;
    }
}

// One batch per block, 512 threads (8 waves), 64KB static LDS -> 2 blocks/CU.
// Wave (h = wid>>1, half = wid&1). LDS region A (64K):
//   q^T[64][512]bf16  ->  ctx'^T[64][512]bf16  ->  Y^T[64][256]bf16 (32K)
// Attention chain (Theta, Phi, G^T, S^T, softmax, P^T, PV) lives in registers:
// MFMA C/D layout (row=(l>>4)*4+r, col=l&15) == 16x16x16 A/B frag layout
// (k=(l>>4)*4+i, row/col=l&15), so D-tiles chain directly into mfma16 operands.
__global__ __launch_bounds__(512, 4)
void lawin_main(const float* __restrict__ query, const float* __restrict__ context,
                const float* __restrict__ pm_b, const float* __restrict__ g_b,
                const float* __restrict__ th_b, const float* __restrict__ ph_b,
                const char* __restrict__ ws, float* __restrict__ out) {
    __shared__ __align__(16) char A[65536];

    const char* pmw = ws + PMW_OFF;
    const char* thw = ws + THW_OFF;
    const char* phw = ws + PHW_OFF;
    const char* gww = ws + GW_OFF;
    const char* oww = ws + OUTW_OFF;
    const float* ob = (const float*)(ws + OUTB_OFF);

    const int b = blockIdx.x;
    const int tid = threadIdx.x;
    const int wid = tid >> 6;
    const int lane = tid & 63;
    const int l15 = lane & 15;
    const int l4 = lane >> 4;
    const int h = wid >> 1;
    const int half = wid & 1;
    const int nqbase = half * 32;

    const float* qb = query + (size_t)b * 32768;
    const float* cb = context + (size_t)b * 32768;
    float* outb = out + (size_t)b * 32768;

    // ---------- T0: q (f32 [512][64]) -> q^T bf16 [64][512] in A ----------
    #pragma unroll
    for (int it = 0; it < 16; ++it) {
        int idx = it * 512 + tid;
        int ch = idx >> 4;
        int tt0 = (idx & 15) * 4;
        f32x4 qv = *(const f32x4*)(qb + idx * 4);
        #pragma unroll
        for (int j = 0; j < 4; ++j) {
            int t = tt0 + j;
            *(unsigned short*)(A + t * 1024 + ((ch * 2) ^ SW(t))) = f2bf(qv[j]);
        }
    }
    __syncthreads();

    // ---------- T1: Theta[d][nq] in regs; d = head slice 64, nq = half slice 32 ----------
    short4v thB[4][2];   // S^T B-frags [kd(d-16-step)][nq-tile]
    {
        f32x4 acc[4][2] = {};
        #pragma unroll 4
        for (int ks = 0; ks < 16; ++ks) {
            const int kb = ks * 64 + l4 * 16;
            short8 a[4], bb[2];
            #pragma unroll
            for (int td = 0; td < 4; ++td)
                a[td] = *(const short8*)(thw + (h * 64 + td * 16 + l15) * 1024 + kb);
            #pragma unroll
            for (int tb = 0; tb < 2; ++tb) {
                int nq = nqbase + tb * 16 + l15;
                bb[tb] = *(const short8*)(A + nq * 1024 + (kb ^ SW(nq)));
            }
            #pragma unroll
            for (int td = 0; td < 4; ++td)
                #pragma unroll
                for (int tb = 0; tb < 2; ++tb)
                    acc[td][tb] = MFMA32(a[td], bb[tb], acc[td][tb]);
        }
        #pragma unroll
        for (int td = 0; td < 4; ++td) {
            f32x4 bv = *(const f32x4*)(th_b + h * 64 + td * 16 + l4 * 4);
            #pragma unroll
            for (int tb = 0; tb < 2; ++tb) {
                f32x4 v = acc[td][tb] + bv;
                thB[td][tb] = pack4(v);
            }
        }
    }
    __syncthreads();

    // ---------- T2: posmix, ctx read direct from global; ctx'^T bf16 -> A ----------
    {
        const int cbase = wid * 64;
        #pragma unroll
        for (int mth = 0; mth < 2; ++mth) {
            f32x4 acc[4][2] = {};
            #pragma unroll
            for (int ks = 0; ks < 2; ++ks) {
                short8 a[4], bb[2];
                #pragma unroll
                for (int ct = 0; ct < 4; ++ct) {
                    int c = cbase + ct * 16 + l15;
                    const float* p = cb + c * 64 + ks * 32 + l4 * 8;
                    f32x4 lo = *(const f32x4*)p;
                    f32x4 hi = *(const f32x4*)(p + 4);
                    a[ct] = pack8(lo, hi);
                }
                const int kb = ks * 64 + l4 * 16;
                #pragma unroll
                for (int mt2 = 0; mt2 < 2; ++mt2) {
                    int m = mth * 32 + mt2 * 16 + l15;
                    bb[mt2] = *(const short8*)(pmw + (h * 64 + m) * 128 + kb);
                }
                #pragma unroll
                for (int ct = 0; ct < 4; ++ct)
                    #pragma unroll
                    for (int mt2 = 0; mt2 < 2; ++mt2)
                        acc[ct][mt2] = MFMA32(a[ct], bb[mt2], acc[ct][mt2]);
            }
            #pragma unroll
            for (int mt2 = 0; mt2 < 2; ++mt2) {
                int m = mth * 32 + mt2 * 16 + l15;
                float pbv = pm_b[h * 64 + m];
                #pragma unroll
                for (int ct = 0; ct < 4; ++ct) {
                    int c0 = cbase + ct * 16 + l4 * 4;
                    us4 pk;
                    #pragma unroll
                    for (int r = 0; r < 4; ++r)
                        pk[r] = f2bf(acc[ct][mt2][r] + pbv + cb[(c0 + r) * 64 + m]);
                    *(us4*)(A + m * 1024 + ((2 * c0) ^ SW(m))) = pk;
                }
            }
        }
    }
    __syncthreads();

    // ---------- T3: attention chain, all in registers ----------
    short4v pB[4][2];    // P^T as PV A-frags [knc-step][nq-tile]
    {
        f32x4 s_acc[4][2] = {};   // S^T [nc-tile][nq-tile]
        #pragma unroll
        for (int dh = 0; dh < 2; ++dh) {
            f32x4 pacc[2][4] = {};   // Phi[d][nc]: [td2][nc-tile]
            #pragma unroll 4
            for (int ks = 0; ks < 16; ++ks) {
                const int kb = ks * 64 + l4 * 16;
                short8 a[2], bb[4];
                #pragma unroll
                for (int td2 = 0; td2 < 2; ++td2)
                    a[td2] = *(const short8*)(phw + (h * 64 + dh * 32 + td2 * 16 + l15) * 1024 + kb);
                #pragma unroll
                for (int tc = 0; tc < 4; ++tc) {
                    int nc = tc * 16 + l15;
                    bb[tc] = *(const short8*)(A + nc * 1024 + (kb ^ SW(nc)));
                }
                #pragma unroll
                for (int td2 = 0; td2 < 2; ++td2)
                    #pragma unroll
                    for (int tc = 0; tc < 4; ++tc)
                        pacc[td2][tc] = MFMA32(a[td2], bb[tc], pacc[td2][tc]);
            }
            #pragma unroll
            for (int td2 = 0; td2 < 2; ++td2) {
                f32x4 bv = *(const f32x4*)(ph_b + h * 64 + dh * 32 + td2 * 16 + l4 * 4);
                short4v phB[4];
                #pragma unroll
                for (int tc = 0; tc < 4; ++tc) {
                    f32x4 v = pacc[td2][tc] + bv;
                    phB[tc] = pack4(v);
                }
                #pragma unroll
                for (int tc = 0; tc < 4; ++tc)
                    #pragma unroll
                    for (int tb = 0; tb < 2; ++tb)
                        s_acc[tc][tb] = mfma16(phB[tc], thB[dh * 2 + td2][tb], s_acc[tc][tb]);
            }
        }
        // softmax over nc (16 per lane + shfl across l4), scale 1/8
        #pragma unroll
        for (int tb = 0; tb < 2; ++tb) {
            float mx = -1e30f;
            #pragma unroll
            for (int tc = 0; tc < 4; ++tc)
                #pragma unroll
                for (int r = 0; r < 4; ++r) mx = fmaxf(mx, s_acc[tc][tb][r]);
            mx = fmaxf(mx, __shfl_xor(mx, 16));
            mx = fmaxf(mx, __shfl_xor(mx, 32));
            float sum = 0.f;
            #pragma unroll
            for (int tc = 0; tc < 4; ++tc)
                #pragma unroll
                for (int r = 0; r < 4; ++r) {
                    float v = __expf((s_acc[tc][tb][r] - mx) * 0.125f);
                    s_acc[tc][tb][r] = v;
                    sum += v;
                }
            sum += __shfl_xor(sum, 16);
            sum += __shfl_xor(sum, 32);
            float rinv = 1.0f / sum;
            #pragma unroll
            for (int tc = 0; tc < 4; ++tc) {
                f32x4 v = s_acc[tc][tb] * rinv;
                pB[tc][tb] = pack4(v);
            }
        }
    }
    f32x4 y_acc[2][4] = {};    // Y^T [nq-tile][dg-tile(4, global)]
    {
        #pragma unroll
        for (int dgh = 0; dgh < 2; ++dgh) {
            f32x4 gacc[4][2] = {};   // G^T[nc][dg]: [tnc][tdg2]
            #pragma unroll 4
            for (int ks = 0; ks < 16; ++ks) {
                const int kb = ks * 64 + l4 * 16;
                short8 a[4], bb[2];
                #pragma unroll
                for (int tnc = 0; tnc < 4; ++tnc) {
                    int nc = tnc * 16 + l15;
                    a[tnc] = *(const short8*)(A + nc * 1024 + (kb ^ SW(nc)));
                }
                #pragma unroll
                for (int tdg2 = 0; tdg2 < 2; ++tdg2)
                    bb[tdg2] = *(const short8*)(gww + (h * 64 + dgh * 32 + tdg2 * 16 + l15) * 1024 + kb);
                #pragma unroll
                for (int tnc = 0; tnc < 4; ++tnc)
                    #pragma unroll
                    for (int tdg2 = 0; tdg2 < 2; ++tdg2)
                        gacc[tnc][tdg2] = MFMA32(a[tnc], bb[tdg2], gacc[tnc][tdg2]);
            }
            #pragma unroll
            for (int tdg2 = 0; tdg2 < 2; ++tdg2) {
                float gbv = g_b[h * 64 + dgh * 32 + tdg2 * 16 + l15];
                short4v gB[4];
                #pragma unroll
                for (int tnc = 0; tnc < 4; ++tnc) {
                    f32x4 v = gacc[tnc][tdg2] + gbv;
                    gB[tnc] = pack4(v);
                }
                #pragma unroll
                for (int tb = 0; tb < 2; ++tb)
                    #pragma unroll
                    for (int tnc = 0; tnc < 4; ++tnc)
                        y_acc[tb][dgh * 2 + tdg2] = mfma16(pB[tnc][tb], gB[tnc], y_acc[tb][dgh * 2 + tdg2]);
            }
        }
    }
    __syncthreads();   // all waves done reading ctx'^T

    // ---------- T4: Y^T bf16 [64][256] -> A[0,32K) ----------
    #pragma unroll
    for (int tb = 0; tb < 2; ++tb)
        #pragma unroll
        for (int tdg = 0; tdg < 4; ++tdg)
            #pragma unroll
            for (int r = 0; r < 4; ++r) {
                int nq = nqbase + tb * 16 + l4 * 4 + r;
                int dg = h * 64 + tdg * 16 + l15;
                *(unsigned short*)(A + nq * 512 + ((2 * dg) ^ SW(nq))) = f2bf(y_acc[tb][tdg][r]);
            }
    __syncthreads();

    // ---------- T5: out-proj (BN folded) + bias + query residual ----------
    {
        const int obase = wid * 64;
        f32x4 acc[4][4] = {};
        #pragma unroll 2
        for (int ks = 0; ks < 8; ++ks) {
            const int kb = ks * 64 + l4 * 16;
            short8 a[4], bb[4];
            #pragma unroll
            for (int tr = 0; tr < 4; ++tr) {
                int tok = tr * 16 + l15;
                a[tr] = *(const short8*)(A + tok * 512 + (kb ^ SW(tok)));
            }
            #pragma unroll
            for (int oc = 0; oc < 4; ++oc)
                bb[oc] = *(const short8*)(oww + (obase + oc * 16 + l15) * 512 + kb);
            #pragma unroll
            for (int tr = 0; tr < 4; ++tr)
                #pragma unroll
                for (int oc = 0; oc < 4; ++oc)
                    acc[tr][oc] = MFMA32(a[tr], bb[oc], acc[tr][oc]);
        }
        #pragma unroll
        for (int oc = 0; oc < 4; ++oc) {
            int o = obase + oc * 16 + l15;
            float bias = ob[o];
            #pragma unroll
            for (int tr = 0; tr < 4; ++tr) {
                int tt = tr * 16 + l4 * 4;
                f32x4 qv = *(const f32x4*)(qb + o * 64 + tt);
                f32x4 ov;
                #pragma unroll
                for (int r = 0; r < 4; ++r) ov[r] = acc[tr][oc][r] + bias + qv[r];
                *(f32x4*)(outb + o * 64 + tt) = ov;
            }
        }
    }
}

extern "C" void kernel_launch(void* const* d_in, const int* in_sizes, int n_in,
                              void* d_out, int out_size, void* d_ws, size_t ws_size,
                              hipStream_t stream) {
    const float* query   = (const float*)d_in[0];
    const float* context = (const float*)d_in[1];
    const float* pm_w    = (const float*)d_in[2];
    const float* pm_b    = (const float*)d_in[3];
    const float* g_w     = (const float*)d_in[4];
    const float* g_b     = (const float*)d_in[5];
    const float* th_w    = (const float*)d_in[6];
    const float* th_b    = (const float*)d_in[7];
    const float* ph_w    = (const float*)d_in[8];
    const float* ph_b    = (const float*)d_in[9];
    const float* out_w   = (const float*)d_in[10];
    const float* gamma   = (const float*)d_in[11];
    const float* beta    = (const float*)d_in[12];
    const float* mean    = (const float*)d_in[13];
    const float* var     = (const float*)d_in[14];
    char* ws = (char*)d_ws;
    float* out = (float*)d_out;

    if (ws_size < WS_BYTES) return;

    prep_kernel<<<512, 256, 0, stream>>>(pm_w, g_w, th_w, ph_w, out_w, gamma, beta, mean, var, ws);
    lawin_main<<<NBATCH, 512, 0, stream>>>(query, context, pm_b, g_b, th_b, ph_b, ws, out);
}